// Round 2
// baseline (137.933 us; speedup 1.0000x reference)
//
#include <hip/hip_runtime.h>
#include <stdint.h>

// Match XLA fp32 semantics: mul and add are separate HLO ops, never contracted
// into FMA. hipcc default is -ffp-contract=fast-honor-pragmas, so this pragma
// is honored; critical chains additionally use __fmul_rn/__fadd_rn.
#pragma clang fp contract(off)

#define NPIX (16 * 256 * 256)  // 1048576 pixels
#define NCAT 8

__device__ __forceinline__ uint32_t rotl32(uint32_t x, int r) {
  return (x << r) | (x >> (32 - r));
}

// threefry2x32 with key (0, 42) [jax.random.key(42)], counter (0, idx),
// returning x0 ^ x1 — the JAX "threefry_partitionable" 32-bit draw.
__device__ __forceinline__ uint32_t tf_bits(uint32_t idx) {
  const uint32_t ks0 = 0u;
  const uint32_t ks1 = 42u;
  const uint32_t ks2 = 0x1BD11BDAu ^ ks0 ^ ks1;
  uint32_t x0 = 0u + ks0;   // counts_hi = 0  (size < 2^32)
  uint32_t x1 = idx + ks1;  // counts_lo = flat index
#define TF4(ra, rb, rc, rd)                  \
  x0 += x1; x1 = rotl32(x1, ra); x1 ^= x0;   \
  x0 += x1; x1 = rotl32(x1, rb); x1 ^= x0;   \
  x0 += x1; x1 = rotl32(x1, rc); x1 ^= x0;   \
  x0 += x1; x1 = rotl32(x1, rd); x1 ^= x0;
  TF4(13, 15, 26, 6)  x0 += ks1; x1 += ks2 + 1u;
  TF4(17, 29, 16, 24) x0 += ks2; x1 += ks0 + 2u;
  TF4(13, 15, 26, 6)  x0 += ks0; x1 += ks1 + 3u;
  TF4(17, 29, 16, 24) x0 += ks1; x1 += ks2 + 4u;
  TF4(13, 15, 26, 6)  x0 += ks2; x1 += ks0 + 5u;
#undef TF4
  return x0 ^ x1;
}

// jax.random.gumbel element: -log(-log(uniform(tiny, 1))), fp32, bit-literal.
__device__ __forceinline__ float gumbel_at(uint32_t idx) {
  const float kTiny = 1.1754943508222875e-38f;  // finfo(f32).tiny
  uint32_t bits = tf_bits(idx);
  // mantissa-fill trick: float in [1,2) minus 1
  float f = __uint_as_float((bits >> 9) | 0x3f800000u) - 1.0f;
  // floats * (maxval - minval) + minval; (1 - tiny) rounds to 1.0f
  f = __fadd_rn(__fmul_rn(f, 1.0f), kTiny);
  f = fmaxf(kTiny, f);
  return -logf(-logf(f));
}

__global__ __launch_bounds__(256) void catdiff_sample_kernel(
    const int* __restrict__ x_t, const float* __restrict__ pred,
    const int* __restrict__ t, const float* __restrict__ Qs,
    const float* __restrict__ Qbs, float* __restrict__ out_idx,
    float* __restrict__ out_probs) {
  __shared__ float sL[64];  // Qs[t[b]]     row-major [row][col]
  __shared__ float sR[64];  // Qbs[t[b]-1]  row-major [X][c]

  const int p = blockIdx.x * 256 + threadIdx.x;  // 256 blocks per batch image
  const int b = p >> 16;                         // batch index (uniform/block)
  const int tb = t[b];                           // 1..999

  if (threadIdx.x < 64) {
    sL[threadIdx.x] = Qs[tb * 64 + threadIdx.x];
  } else if (threadIdx.x < 128) {
    sR[threadIdx.x - 64] = Qbs[(tb - 1) * 64 + (threadIdx.x - 64)];
  }
  __syncthreads();

  const int xt = x_t[p];  // 0..7

  // left[c] = Qs[tb, c, x_t]   (8 distinct LDS addrs per read -> conflict-free)
  float left[NCAT];
#pragma unroll
  for (int c = 0; c < NCAT; ++c) left[c] = sL[c * 8 + xt];

  // x_probs = softmax(pred[p, :])  — max, exp(x - max), ascending sum, divide
  const float4 pr0 = *reinterpret_cast<const float4*>(pred + (size_t)p * 8);
  const float4 pr1 = *reinterpret_cast<const float4*>(pred + (size_t)p * 8 + 4);
  float lg[NCAT] = {pr0.x, pr0.y, pr0.z, pr0.w, pr1.x, pr1.y, pr1.z, pr1.w};
  float m = lg[0];
#pragma unroll
  for (int c = 1; c < NCAT; ++c) m = fmaxf(m, lg[c]);
  float e[NCAT];
#pragma unroll
  for (int c = 0; c < NCAT; ++c) e[c] = expf(lg[c] - m);
  float s = 0.0f;
#pragma unroll
  for (int c = 0; c < NCAT; ++c) s = __fadd_rn(s, e[c]);
  float xp[NCAT];
#pragma unroll
  for (int c = 0; c < NCAT; ++c) xp[c] = e[c] / s;

  // posterior[X,c] = left[c] * Qbs[t-1, X, c]; normalized over c; contracted
  // against xp[X]:  anc[c] = sum_X (left[c]*R[X,c]/denom[X]) * xp[X]
  float anc[NCAT];
#pragma unroll
  for (int c = 0; c < NCAT; ++c) anc[c] = 0.0f;
#pragma unroll
  for (int X = 0; X < NCAT; ++X) {
    float denom = 0.0f;
#pragma unroll
    for (int c = 0; c < NCAT; ++c)
      denom = __fadd_rn(denom, __fmul_rn(left[c], sR[X * 8 + c]));
#pragma unroll
    for (int c = 0; c < NCAT; ++c) {
      float post = __fmul_rn(left[c], sR[X * 8 + c]) / denom;
      anc[c] = __fadd_rn(anc[c], __fmul_rn(post, xp[X]));
    }
  }

  // x_{t-1} = argmax_c log(anc[c]) + gumbel   (first-max on ties, like argmax)
  const uint32_t gbase = (uint32_t)p * 8u;
  float bestv = __fadd_rn(logf(anc[0]), gumbel_at(gbase + 0u));
  int besti = 0;
#pragma unroll
  for (int c = 1; c < NCAT; ++c) {
    float v = __fadd_rn(logf(anc[c]), gumbel_at(gbase + (uint32_t)c));
    if (v > bestv) { bestv = v; besti = c; }
  }

  // t >= 1 always (randint(1, T)), so out = x_{t-1} everywhere.
  out_idx[p] = (float)besti;  // mixed tuple -> harness reads buffer as f32
  float4 o0 = make_float4(anc[0], anc[1], anc[2], anc[3]);
  float4 o1 = make_float4(anc[4], anc[5], anc[6], anc[7]);
  *reinterpret_cast<float4*>(out_probs + (size_t)p * 8) = o0;
  *reinterpret_cast<float4*>(out_probs + (size_t)p * 8 + 4) = o1;
}

extern "C" void kernel_launch(void* const* d_in, const int* in_sizes, int n_in,
                              void* d_out, int out_size, void* d_ws,
                              size_t ws_size, hipStream_t stream) {
  (void)in_sizes; (void)n_in; (void)out_size; (void)d_ws; (void)ws_size;
  const int*   x_t  = (const int*)d_in[0];
  const float* pred = (const float*)d_in[1];
  const int*   t    = (const int*)d_in[2];
  const float* Qs   = (const float*)d_in[3];
  const float* Qbs  = (const float*)d_in[4];
  float* out0 = (float*)d_out;          // argmax indices as f32 (1048576)
  float* out1 = out0 + NPIX;            // ancestral_probs     (8388608)

  dim3 grid(NPIX / 256), block(256);
  hipLaunchKernelGGL(catdiff_sample_kernel, grid, block, 0, stream,
                     x_t, pred, t, Qs, Qbs, out0, out1);
}

// Round 4
// 117.375 us; speedup vs baseline: 1.1751x; 1.1751x over previous
//
#include <hip/hip_runtime.h>
#include <stdint.h>

// Match XLA fp32 semantics: mul and add are separate HLO ops, never contracted
// into FMA. hipcc default is -ffp-contract=fast-honor-pragmas, so this pragma
// is honored; critical chains additionally use __fmul_rn/__fadd_rn.
#pragma clang fp contract(off)

#define NPIX (16 * 256 * 256)  // 1048576 pixels
#define NCAT 8
// Posterior-matrix LDS row stride in words. 260 % 32 == 4 -> for a fixed X,
// the 8 possible x_t rows map to 8 disjoint 4-bank quads => ds_read_b128 is
// bank-conflict-free across lanes with mixed x_t. 260*4 = 1040 B, 16B-aligned.
#define MSTRIDE 260

__device__ __forceinline__ uint32_t rotl32(uint32_t x, int r) {
  return (x << r) | (x >> (32 - r));
}

// threefry2x32 with key (0, 42) [jax.random.key(42)], counter (0, idx),
// returning x0 ^ x1 — the JAX "threefry_partitionable" 32-bit draw.
// Verified bit-exact vs reference in round 2 (zero argmax flips).
__device__ __forceinline__ uint32_t tf_bits(uint32_t idx) {
  const uint32_t ks0 = 0u;
  const uint32_t ks1 = 42u;
  const uint32_t ks2 = 0x1BD11BDAu ^ ks0 ^ ks1;
  uint32_t x0 = 0u + ks0;   // counts_hi = 0  (size < 2^32)
  uint32_t x1 = idx + ks1;  // counts_lo = flat index
#define TF4(ra, rb, rc, rd)                  \
  x0 += x1; x1 = rotl32(x1, ra); x1 ^= x0;   \
  x0 += x1; x1 = rotl32(x1, rb); x1 ^= x0;   \
  x0 += x1; x1 = rotl32(x1, rc); x1 ^= x0;   \
  x0 += x1; x1 = rotl32(x1, rd); x1 ^= x0;
  TF4(13, 15, 26, 6)  x0 += ks1; x1 += ks2 + 1u;
  TF4(17, 29, 16, 24) x0 += ks2; x1 += ks0 + 2u;
  TF4(13, 15, 26, 6)  x0 += ks0; x1 += ks1 + 3u;
  TF4(17, 29, 16, 24) x0 += ks1; x1 += ks2 + 4u;
  TF4(13, 15, 26, 6)  x0 += ks2; x1 += ks0 + 5u;
#undef TF4
  return x0 ^ x1;
}

// jax.random.gumbel element: -log(-log(uniform(tiny, 1))), fp32, bit-literal.
__device__ __forceinline__ float gumbel_at(uint32_t idx) {
  const float kTiny = 1.1754943508222875e-38f;  // finfo(f32).tiny
  uint32_t bits = tf_bits(idx);
  float f = __uint_as_float((bits >> 9) | 0x3f800000u) - 1.0f;
  f = __fadd_rn(__fmul_rn(f, 1.0f), kTiny);
  f = fmaxf(kTiny, f);
  return -logf(-logf(f));
}

__global__ __launch_bounds__(256) void catdiff_sample_kernel(
    const int* __restrict__ x_t, const float* __restrict__ pred,
    const int* __restrict__ t, const float* __restrict__ Qs,
    const float* __restrict__ Qbs, float* __restrict__ out_idx,
    float* __restrict__ out_probs) {
  __shared__ float sL[64];           // Qs[t[b]]      [c][xt]... row-major [row][col]
  __shared__ float sR[64];           // Qbs[t[b]-1]   [X][c]
  __shared__ float sDen[64];         // denom[xt][X]
  __shared__ float sM[8 * MSTRIDE];  // normalized posterior M[xt][X][c], padded

  const int tid = threadIdx.x;
  const int p = blockIdx.x * 256 + tid;
  const int b = blockIdx.x >> 8;  // 256 blocks per batch image (block-uniform)

  // Issue global loads first so HBM latency hides under the precompute phase.
  const float4 pr0 = *reinterpret_cast<const float4*>(pred + (size_t)p * 8);
  const float4 pr1 = *reinterpret_cast<const float4*>(pred + (size_t)p * 8 + 4);
  const int xt = x_t[p];  // 0..7
  const int tb = t[b];    // 1..999 (scalar load, block-uniform)

  // ---- Per-block posterior precompute (bit-identical op order to reference:
  //      denom[X] = sum_c fmul(left[c], R[X,c]) ascending; M = fmul(..)/denom).
  if (tid < 64) {
    sL[tid] = Qs[tb * 64 + tid];
  } else if (tid < 128) {
    sR[tid - 64] = Qbs[(tb - 1) * 64 + (tid - 64)];
  }
  __syncthreads();

  if (tid < 64) {
    const int x = tid >> 3;  // hypothetical x_t value
    const int X = tid & 7;   // posterior row
    float d = 0.0f;
#pragma unroll
    for (int c = 0; c < NCAT; ++c)
      d = __fadd_rn(d, __fmul_rn(sL[c * 8 + x], sR[X * 8 + c]));
    sDen[tid] = d;
  }
  __syncthreads();

  {
    // 512 entries over 256 threads, 2 each: e = (xt<<6)|(X<<3)|c
#pragma unroll
    for (int k = 0; k < 2; ++k) {
      const int e = tid * 2 + k;
      const int x = e >> 6, X = (e >> 3) & 7, c = e & 7;
      sM[x * MSTRIDE + X * 8 + c] =
          __fmul_rn(sL[c * 8 + x], sR[X * 8 + c]) / sDen[(x << 3) | X];
    }
  }
  __syncthreads();

  // ---- x_probs = softmax(pred[p, :]) — max, exp(x-max), ascending sum, div
  float lg[NCAT] = {pr0.x, pr0.y, pr0.z, pr0.w, pr1.x, pr1.y, pr1.z, pr1.w};
  float m = lg[0];
#pragma unroll
  for (int c = 1; c < NCAT; ++c) m = fmaxf(m, lg[c]);
  float e[NCAT];
#pragma unroll
  for (int c = 0; c < NCAT; ++c) e[c] = expf(lg[c] - m);
  float s = 0.0f;
#pragma unroll
  for (int c = 0; c < NCAT; ++c) s = __fadd_rn(s, e[c]);
  float xp[NCAT];
#pragma unroll
  for (int c = 0; c < NCAT; ++c) xp[c] = e[c] / s;

  // ---- anc[c] = sum_X M[xt][X][c] * xp[X]  (ascending X, mul+add uncontracted)
  float anc[NCAT];
#pragma unroll
  for (int c = 0; c < NCAT; ++c) anc[c] = 0.0f;
  const float* Mrow = &sM[xt * MSTRIDE];
#pragma unroll
  for (int X = 0; X < NCAT; ++X) {
    const float4 m0 = *reinterpret_cast<const float4*>(Mrow + X * 8);
    const float4 m1 = *reinterpret_cast<const float4*>(Mrow + X * 8 + 4);
    anc[0] = __fadd_rn(anc[0], __fmul_rn(m0.x, xp[X]));
    anc[1] = __fadd_rn(anc[1], __fmul_rn(m0.y, xp[X]));
    anc[2] = __fadd_rn(anc[2], __fmul_rn(m0.z, xp[X]));
    anc[3] = __fadd_rn(anc[3], __fmul_rn(m0.w, xp[X]));
    anc[4] = __fadd_rn(anc[4], __fmul_rn(m1.x, xp[X]));
    anc[5] = __fadd_rn(anc[5], __fmul_rn(m1.y, xp[X]));
    anc[6] = __fadd_rn(anc[6], __fmul_rn(m1.z, xp[X]));
    anc[7] = __fadd_rn(anc[7], __fmul_rn(m1.w, xp[X]));
  }

  // ---- x_{t-1} = argmax_c log(anc[c]) + gumbel (first-max ties, like argmax)
  const uint32_t gbase = (uint32_t)p * 8u;
  float bestv = __fadd_rn(logf(anc[0]), gumbel_at(gbase + 0u));
  int besti = 0;
#pragma unroll
  for (int c = 1; c < NCAT; ++c) {
    float v = __fadd_rn(logf(anc[c]), gumbel_at(gbase + (uint32_t)c));
    if (v > bestv) { bestv = v; besti = c; }
  }

  // t >= 1 always (randint(1, T)), so out = x_{t-1} everywhere.
  out_idx[p] = (float)besti;  // mixed tuple -> harness reads buffer as f32
  float4 o0 = make_float4(anc[0], anc[1], anc[2], anc[3]);
  float4 o1 = make_float4(anc[4], anc[5], anc[6], anc[7]);
  *reinterpret_cast<float4*>(out_probs + (size_t)p * 8) = o0;
  *reinterpret_cast<float4*>(out_probs + (size_t)p * 8 + 4) = o1;
}

extern "C" void kernel_launch(void* const* d_in, const int* in_sizes, int n_in,
                              void* d_out, int out_size, void* d_ws,
                              size_t ws_size, hipStream_t stream) {
  (void)in_sizes; (void)n_in; (void)out_size; (void)d_ws; (void)ws_size;
  const int*   x_t  = (const int*)d_in[0];
  const float* pred = (const float*)d_in[1];
  const int*   t    = (const int*)d_in[2];
  const float* Qs   = (const float*)d_in[3];
  const float* Qbs  = (const float*)d_in[4];
  float* out0 = (float*)d_out;          // argmax indices as f32 (1048576)
  float* out1 = out0 + NPIX;            // ancestral_probs     (8388608)

  dim3 grid(NPIX / 256), block(256);
  hipLaunchKernelGGL(catdiff_sample_kernel, grid, block, 0, stream,
                     x_t, pred, t, Qs, Qbs, out0, out1);
}